// Round 3
// baseline (371.791 us; speedup 1.0000x reference)
//
#include <hip/hip_runtime.h>
#include <hip/hip_bf16.h>

#define BB 4
#define CC 256
#define NN 4096
#define NSPLIT 4
#define KSPLIT (NN / NSPLIT)

typedef __attribute__((ext_vector_type(8))) short short8;
typedef __attribute__((ext_vector_type(4))) float floatx4;
typedef __attribute__((ext_vector_type(4))) unsigned short ushortx4;

__device__ __forceinline__ float bf2f(unsigned short u) {
  union { unsigned int i; float f; } cv; cv.i = ((unsigned int)u) << 16; return cv.f;
}
__device__ __forceinline__ unsigned short f2bf(float f) {
  union { __hip_bfloat16 h; unsigned short u; } cv; cv.h = __float2bfloat16(f); return cv.u;
}

#define MFMA(a, b, c) __builtin_amdgcn_mfma_f32_16x16x32_bf16((a), (b), (c), 0, 0, 0)

// ---------------------------------------------------------------------------
// Phase 0: fp32 weights -> bf16.
// ---------------------------------------------------------------------------
__global__ __launch_bounds__(256) void wcvt(const float* __restrict__ w0,
                                            const float* __restrict__ w1,
                                            const float* __restrict__ w2,
                                            unsigned short* __restrict__ o0,
                                            unsigned short* __restrict__ o1,
                                            unsigned short* __restrict__ o2) {
  const float* w = (blockIdx.y == 0) ? w0 : (blockIdx.y == 1) ? w1 : w2;
  unsigned short* o = (blockIdx.y == 0) ? o0 : (blockIdx.y == 1) ? o1 : o2;
  int i = (blockIdx.x * 256 + threadIdx.x) * 4;
  floatx4 v = *(const floatx4*)&w[i];
  ushortx4 p;
#pragma unroll
  for (int r = 0; r < 4; r++) p[r] = f2bf(v[r]);
  *(ushortx4*)&o[i] = p;
}

// ---------------------------------------------------------------------------
// Phase 1: Xbf[b][n][c] = bf16( x[b][c][n] + PE(c, n) ), LDS transpose.
// ---------------------------------------------------------------------------
__global__ __launch_bounds__(256) void prep_x(const float* __restrict__ x,
                                              unsigned short* __restrict__ Xbf) {
  __shared__ float tile[32][33];
  int b = blockIdx.z;
  int n0 = blockIdx.x * 32, c0 = blockIdx.y * 32;
  int tx = threadIdx.x, ty = threadIdx.y;
#pragma unroll
  for (int i = 0; i < 4; i++) {
    int c = c0 + ty + i * 8;
    int n = n0 + tx;
    float v = x[((long)(b * CC + c)) * NN + n];
    int hh = n >> 6, ww = n & 63;
    int j = c & 63;
    float freq = exp2f(-0.2076205059304601f * (float)j);  // 10000^(-j/64)
    float arg = (float)((c < 128) ? ww : hh) * freq;
    v += (c & 64) ? cosf(arg) : sinf(arg);
    tile[ty + i * 8][tx] = v;
  }
  __syncthreads();
#pragma unroll
  for (int i = 0; i < 4; i++) {
    int n = n0 + ty + i * 8;
    int c = c0 + tx;
    Xbf[((long)(b * NN + n)) * CC + c] = f2bf(tile[tx][ty + i * 8]);
  }
}

// ---------------------------------------------------------------------------
// Phase 2: C = A * Bt^T bf16, K=256. 64x64 tile/WG (m92 convention).
// ---------------------------------------------------------------------------
__global__ __launch_bounds__(256, 2) void gemm_bt(const unsigned short* __restrict__ A, long asb,
                                                  const unsigned short* __restrict__ Bt, long bsb,
                                                  unsigned short* __restrict__ O, long osb,
                                                  int Nc) {
  __shared__ alignas(16) unsigned short Al[64][40];
  __shared__ alignas(16) unsigned short Bl[64][40];
  int b = blockIdx.z;
  const unsigned short* Ab = A + (long)b * asb;
  const unsigned short* Bb = Bt + (long)b * bsb;
  unsigned short* Ob = O + (long)b * osb;
  long row0 = (long)blockIdx.y * 64, col0 = (long)blockIdx.x * 64;
  int t = threadIdx.x, wave = t >> 6, lane = t & 63, quad = lane >> 4, l15 = lane & 15;
  int sr = t >> 2, sk = (t & 3) * 8;
  floatx4 acc[4] = {};
#pragma unroll
  for (int k0 = 0; k0 < 256; k0 += 32) {
    short8 av = *(const short8*)&Ab[(row0 + sr) * 256 + k0 + sk];
    short8 bv = *(const short8*)&Bb[(col0 + sr) * 256 + k0 + sk];
    __syncthreads();
    *(short8*)&Al[sr][sk] = av;
    *(short8*)&Bl[sr][sk] = bv;
    __syncthreads();
    short8 af = *(const short8*)&Al[wave * 16 + l15][quad * 8];
#pragma unroll
    for (int cb = 0; cb < 4; cb++) {
      short8 bf = *(const short8*)&Bl[cb * 16 + l15][quad * 8];
      acc[cb] = MFMA(af, bf, acc[cb]);
    }
  }
#pragma unroll
  for (int cb = 0; cb < 4; cb++) {
#pragma unroll
    for (int r = 0; r < 4; r++) {
      long row = row0 + wave * 16 + quad * 4 + r;
      long col = col0 + cb * 16 + l15;
      Ob[row * (long)Nc + col] = f2bf(acc[cb][r]);
    }
  }
}

// ---------------------------------------------------------------------------
// Phase 3: flash attention, KV-split. Grid (N/64, NSPLIT, B); WG = 4 waves,
// wave owns 16 q-rows over KSPLIT keys. Fragment-major LDS (conflict-free):
//   Klf[(mt*8+ks)*64 + lane][8] : element K[m0+mt*16+l15][ks*32+quad*8+j]
//   Vlf[db*64 + lane][8]        : element Vt[db*16+l15][m0+quad*8+j]
//   Plf[wave][lane][8]          : A-frag  P[l15][quad*8+j]
// Writes unnormalized partial O (bf16) + per-row m,l.
// ---------------------------------------------------------------------------
__global__ __launch_bounds__(256, 4) void attn(const unsigned short* __restrict__ Qg,
                                               const unsigned short* __restrict__ Kg,
                                               const unsigned short* __restrict__ Vtg,
                                               unsigned short* __restrict__ Opart,
                                               float* __restrict__ Mp,
                                               float* __restrict__ Lp) {
  __shared__ alignas(16) unsigned short Klf[16 * 64 * 8];
  __shared__ alignas(16) unsigned short Vlf[16 * 64 * 8];
  __shared__ alignas(16) unsigned short Plf[4][512];
  int b = blockIdx.z, sp = blockIdx.y;
  long q0 = (long)blockIdx.x * 64;
  int t = threadIdx.x, wave = t >> 6, lane = t & 63, quad = lane >> 4, l15 = lane & 15;
  const unsigned short* Qb = Qg + (long)b * NN * CC;
  const unsigned short* Kb = Kg + (long)b * NN * CC;
  const unsigned short* Vb = Vtg + (long)b * CC * NN;

  // Q fragments (A-layout), k = d in [0,256)
  short8 qf[8];
  long qrow = q0 + wave * 16 + l15;
#pragma unroll
  for (int ks = 0; ks < 8; ks++)
    qf[ks] = *(const short8*)&Qb[qrow * 256 + ks * 32 + quad * 8];

  floatx4 acc[16] = {};
  float mrow[4] = {-INFINITY, -INFINITY, -INFINITY, -INFINITY};
  float lrow[4] = {0.f, 0.f, 0.f, 0.f};

  const float sc = 0.0625f * 1.4426950408889634f;  // scale * log2(e)
  const int kbeg = sp * KSPLIT, kend = kbeg + KSPLIT;

  for (int m0 = kbeg; m0 < kend; m0 += 32) {
    __syncthreads();  // previous tile fully consumed
#pragma unroll
    for (int st = 0; st < 4; st++) {
      int fg = st * 4 + wave;  // 0..15: K frag group / V d-block
      int mt = fg >> 3, ks = fg & 7;
      short8 kv = *(const short8*)&Kb[(long)(m0 + mt * 16 + l15) * 256 + ks * 32 + quad * 8];
      short8 vv = *(const short8*)&Vb[(long)(fg * 16 + l15) * NN + m0 + quad * 8];
      *(short8*)&Klf[(fg * 64 + lane) * 8] = kv;
      *(short8*)&Vlf[(fg * 64 + lane) * 8] = vv;
    }
    __syncthreads();

    // S = Q K^T : 16 q-rows x 32 keys per wave
    floatx4 s[2];
    {
      floatx4 z = {0.f, 0.f, 0.f, 0.f};
      s[0] = z; s[1] = z;
    }
#pragma unroll
    for (int ks = 0; ks < 8; ks++) {
      short8 kf0 = *(const short8*)&Klf[(ks * 64 + lane) * 8];
      s[0] = MFMA(qf[ks], kf0, s[0]);
      short8 kf1 = *(const short8*)&Klf[((8 + ks) * 64 + lane) * 8];
      s[1] = MFMA(qf[ks], kf1, s[1]);
    }

    // online softmax (exp2 domain); row r = quad*4+r, width-16 reductions
    float mn[4], al[4];
#pragma unroll
    for (int r = 0; r < 4; r++) {
      s[0][r] *= sc;
      s[1][r] *= sc;
      float v = fmaxf(s[0][r], s[1][r]);
      v = fmaxf(v, __shfl_xor(v, 1));
      v = fmaxf(v, __shfl_xor(v, 2));
      v = fmaxf(v, __shfl_xor(v, 4));
      v = fmaxf(v, __shfl_xor(v, 8));
      mn[r] = fmaxf(mrow[r], v);
      al[r] = exp2f(mrow[r] - mn[r]);
      mrow[r] = mn[r];
    }
#pragma unroll
    for (int r = 0; r < 4; r++) {
      unsigned short pb0 = f2bf(exp2f(s[0][r] - mn[r]));
      unsigned short pb1 = f2bf(exp2f(s[1][r] - mn[r]));
      float rs = bf2f(pb0) + bf2f(pb1);
      rs += __shfl_xor(rs, 1);
      rs += __shfl_xor(rs, 2);
      rs += __shfl_xor(rs, 4);
      rs += __shfl_xor(rs, 8);
      lrow[r] = lrow[r] * al[r] + rs;
      // P[m=quad*4+r][k] at A-frag offset ((k>>3)*16 + m)*8 + (k&7)
      int m = quad * 4 + r;
      Plf[wave][((l15 >> 3) * 16 + m) * 8 + (l15 & 7)] = pb0;          // k = l15
      Plf[wave][((2 + (l15 >> 3)) * 16 + m) * 8 + (l15 & 7)] = pb1;    // k = 16+l15
    }
#pragma unroll
    for (int db = 0; db < 16; db++) {
      acc[db][0] *= al[0];
      acc[db][1] *= al[1];
      acc[db][2] *= al[2];
      acc[db][3] *= al[3];
    }
    __asm__ volatile("" ::: "memory");  // keep P writes before frag re-read
    short8 pf = *(const short8*)&Plf[wave][lane * 8];
#pragma unroll
    for (int db = 0; db < 16; db++) {
      short8 vf = *(const short8*)&Vlf[(db * 64 + lane) * 8];
      acc[db] = MFMA(pf, vf, acc[db]);
    }
  }

  // epilogue: partial O (unnormalized, at scale 2^-m) + m,l
  unsigned short* Ob = Opart + (long)(b * NSPLIT + sp) * CC * NN;
  long nidx = q0 + wave * 16 + quad * 4;
#pragma unroll
  for (int db = 0; db < 16; db++) {
    long d = db * 16 + l15;
    ushortx4 pk;
#pragma unroll
    for (int r = 0; r < 4; r++) pk[r] = f2bf(acc[db][r]);
    *(ushortx4*)&Ob[d * NN + nidx] = pk;
  }
  if (l15 == 0) {
#pragma unroll
    for (int r = 0; r < 4; r++) {
      long n = nidx + r;
      Mp[(long)(b * NSPLIT + sp) * NN + n] = mrow[r];
      Lp[(long)(b * NSPLIT + sp) * NN + n] = lrow[r];
    }
  }
}

// ---------------------------------------------------------------------------
// Phase 4: combine the NSPLIT partials. Block = 64 d x 64 n.
// ---------------------------------------------------------------------------
__global__ __launch_bounds__(256) void combine(const unsigned short* __restrict__ Op,
                                               const float* __restrict__ Mp,
                                               const float* __restrict__ Lp,
                                               float* __restrict__ Out) {
  __shared__ float Wl[NSPLIT][64];
  int b = blockIdx.z;
  int d0 = blockIdx.y * 64, n0 = blockIdx.x * 64;
  int t = threadIdx.x;
  if (t < 64) {
    int n = n0 + t;
    float ms[NSPLIT], ls[NSPLIT];
#pragma unroll
    for (int s = 0; s < NSPLIT; s++) {
      ms[s] = Mp[(long)(b * NSPLIT + s) * NN + n];
      ls[s] = Lp[(long)(b * NSPLIT + s) * NN + n];
    }
    float M = ms[0];
#pragma unroll
    for (int s = 1; s < NSPLIT; s++) M = fmaxf(M, ms[s]);
    float es[NSPLIT], L = 0.f;
#pragma unroll
    for (int s = 0; s < NSPLIT; s++) {
      es[s] = exp2f(ms[s] - M);
      L += es[s] * ls[s];
    }
    float inv = 1.0f / L;
#pragma unroll
    for (int s = 0; s < NSPLIT; s++) Wl[s][t] = es[s] * inv;
  }
  __syncthreads();
  int tn = t & 15, td = t >> 4;
  int nb = n0 + tn * 4;
  float w[NSPLIT][4];
#pragma unroll
  for (int s = 0; s < NSPLIT; s++)
#pragma unroll
    for (int r = 0; r < 4; r++) w[s][r] = Wl[s][tn * 4 + r];
#pragma unroll
  for (int dd = 0; dd < 4; dd++) {
    int d = d0 + td * 4 + dd;
    floatx4 o = {0.f, 0.f, 0.f, 0.f};
#pragma unroll
    for (int s = 0; s < NSPLIT; s++) {
      ushortx4 pv = *(const ushortx4*)&Op[((long)(b * NSPLIT + s) * CC + d) * NN + nb];
#pragma unroll
      for (int r = 0; r < 4; r++) o[r] += w[s][r] * bf2f(pv[r]);
    }
    *(floatx4*)&Out[((long)b * CC + d) * NN + nb] = o;
  }
}

// ---------------------------------------------------------------------------
extern "C" void kernel_launch(void* const* d_in, const int* in_sizes, int n_in,
                              void* d_out, int out_size, void* d_ws, size_t ws_size,
                              hipStream_t stream) {
  const float* x = (const float*)d_in[0];
  const float* wq = (const float*)d_in[1];
  const float* wk = (const float*)d_in[2];
  const float* wv = (const float*)d_in[3];
  float* out = (float*)d_out;

  char* ws = (char*)d_ws;
  unsigned short* Qbuf = (unsigned short*)(ws);              // 8 MB (B,N,C)
  unsigned short* Kbuf = (unsigned short*)(ws + (8l << 20)); // 8 MB (B,N,C)
  unsigned short* Vt = (unsigned short*)(ws + (16l << 20));  // 8 MB (B,C,N)
  // Xbf lives at [24M,32M) during prep+gemms; Opart [24M,56M) written only by
  // attn, after Xbf is dead -> safe overlap.
  unsigned short* Xbf = (unsigned short*)(ws + (24l << 20));   // 8 MB (B,N,C)
  unsigned short* Opart = (unsigned short*)(ws + (24l << 20)); // 32 MB (B,S,C,N) bf16
  float* Mp = (float*)(ws + (56l << 20));                      // 256 KB
  float* Lp = (float*)(ws + (56l << 20) + (256l << 10));       // 256 KB
  unsigned short* Wq = (unsigned short*)(ws + (57l << 20));
  unsigned short* Wk = (unsigned short*)(ws + (57l << 20) + (1 << 17));
  unsigned short* Wv = (unsigned short*)(ws + (57l << 20) + (2 << 17));

  wcvt<<<dim3(CC * CC / 1024, 3), 256, 0, stream>>>(wq, wk, wv, Wq, Wk, Wv);
  prep_x<<<dim3(NN / 32, CC / 32, BB), dim3(32, 8), 0, stream>>>(x, Xbf);
  gemm_bt<<<dim3(CC / 64, NN / 64, BB), 256, 0, stream>>>(Xbf, (long)NN * CC, Wq, 0, Qbuf,
                                                          (long)NN * CC, CC);
  gemm_bt<<<dim3(CC / 64, NN / 64, BB), 256, 0, stream>>>(Xbf, (long)NN * CC, Wk, 0, Kbuf,
                                                          (long)NN * CC, CC);
  gemm_bt<<<dim3(NN / 64, CC / 64, BB), 256, 0, stream>>>(Wv, 0, Xbf, (long)NN * CC, Vt,
                                                          (long)CC * NN, NN);
  attn<<<dim3(NN / 64, NSPLIT, BB), 256, 0, stream>>>(Qbuf, Kbuf, Vt, Opart, Mp, Lp);
  combine<<<dim3(NN / 64, CC / 64, BB), 256, 0, stream>>>(Opart, Mp, Lp, out);
}

// Round 4
// 306.815 us; speedup vs baseline: 1.2118x; 1.2118x over previous
//
#include <hip/hip_runtime.h>
#include <hip/hip_bf16.h>

#define BB 4
#define CC 256
#define NN 4096
#define NSPLIT 4
#define KSPLIT (NN / NSPLIT)
#define NT (KSPLIT / 32)

typedef __attribute__((ext_vector_type(8))) short short8;
typedef __attribute__((ext_vector_type(4))) float floatx4;
typedef __attribute__((ext_vector_type(4))) unsigned short ushortx4;

__device__ __forceinline__ float bf2f(unsigned short u) {
  union { unsigned int i; float f; } cv; cv.i = ((unsigned int)u) << 16; return cv.f;
}
__device__ __forceinline__ unsigned short f2bf(float f) {
  union { __hip_bfloat16 h; unsigned short u; } cv; cv.h = __float2bfloat16(f); return cv.u;
}

#define MFMA(a, b, c) __builtin_amdgcn_mfma_f32_16x16x32_bf16((a), (b), (c), 0, 0, 0)

// async global->LDS DMA, 16B/lane, LDS dest = wave-uniform base + lane*16
__device__ __forceinline__ void dma16(const unsigned short* g, unsigned short* l) {
  __builtin_amdgcn_global_load_lds(
      (const __attribute__((address_space(1))) unsigned int*)g,
      (__attribute__((address_space(3))) unsigned int*)l, 16, 0, 0);
}
#define S_BARRIER __builtin_amdgcn_s_barrier()
#define MEMFENCE __asm__ volatile("" ::: "memory")

// ---------------------------------------------------------------------------
// Phase 0: fp32 weights -> bf16.
// ---------------------------------------------------------------------------
__global__ __launch_bounds__(256) void wcvt(const float* __restrict__ w0,
                                            const float* __restrict__ w1,
                                            const float* __restrict__ w2,
                                            unsigned short* __restrict__ o0,
                                            unsigned short* __restrict__ o1,
                                            unsigned short* __restrict__ o2) {
  const float* w = (blockIdx.y == 0) ? w0 : (blockIdx.y == 1) ? w1 : w2;
  unsigned short* o = (blockIdx.y == 0) ? o0 : (blockIdx.y == 1) ? o1 : o2;
  int i = (blockIdx.x * 256 + threadIdx.x) * 4;
  floatx4 v = *(const floatx4*)&w[i];
  ushortx4 p;
#pragma unroll
  for (int r = 0; r < 4; r++) p[r] = f2bf(v[r]);
  *(ushortx4*)&o[i] = p;
}

// ---------------------------------------------------------------------------
// Phase 1: Xbf[b][n][c] = bf16( x[b][c][n] + PE(c, n) ), LDS transpose.
// ---------------------------------------------------------------------------
__global__ __launch_bounds__(256) void prep_x(const float* __restrict__ x,
                                              unsigned short* __restrict__ Xbf) {
  __shared__ float tile[32][33];
  int b = blockIdx.z;
  int n0 = blockIdx.x * 32, c0 = blockIdx.y * 32;
  int tx = threadIdx.x, ty = threadIdx.y;
#pragma unroll
  for (int i = 0; i < 4; i++) {
    int c = c0 + ty + i * 8;
    int n = n0 + tx;
    float v = x[((long)(b * CC + c)) * NN + n];
    int hh = n >> 6, ww = n & 63;
    int j = c & 63;
    float freq = exp2f(-0.2076205059304601f * (float)j);  // 10000^(-j/64)
    float arg = (float)((c < 128) ? ww : hh) * freq;
    v += (c & 64) ? cosf(arg) : sinf(arg);
    tile[ty + i * 8][tx] = v;
  }
  __syncthreads();
#pragma unroll
  for (int i = 0; i < 4; i++) {
    int n = n0 + ty + i * 8;
    int c = c0 + tx;
    Xbf[((long)(b * NN + n)) * CC + c] = f2bf(tile[tx][ty + i * 8]);
  }
}

// ---------------------------------------------------------------------------
// Phase 2: C = A * Bt^T bf16, K=256. 64x64 tile/WG (m92 convention).
// ---------------------------------------------------------------------------
__global__ __launch_bounds__(256, 2) void gemm_bt(const unsigned short* __restrict__ A, long asb,
                                                  const unsigned short* __restrict__ Bt, long bsb,
                                                  unsigned short* __restrict__ O, long osb,
                                                  int Nc) {
  __shared__ alignas(16) unsigned short Al[64][40];
  __shared__ alignas(16) unsigned short Bl[64][40];
  int b = blockIdx.z;
  const unsigned short* Ab = A + (long)b * asb;
  const unsigned short* Bb = Bt + (long)b * bsb;
  unsigned short* Ob = O + (long)b * osb;
  long row0 = (long)blockIdx.y * 64, col0 = (long)blockIdx.x * 64;
  int t = threadIdx.x, wave = t >> 6, lane = t & 63, quad = lane >> 4, l15 = lane & 15;
  int sr = t >> 2, sk = (t & 3) * 8;
  floatx4 acc[4] = {};
#pragma unroll
  for (int k0 = 0; k0 < 256; k0 += 32) {
    short8 av = *(const short8*)&Ab[(row0 + sr) * 256 + k0 + sk];
    short8 bv = *(const short8*)&Bb[(col0 + sr) * 256 + k0 + sk];
    __syncthreads();
    *(short8*)&Al[sr][sk] = av;
    *(short8*)&Bl[sr][sk] = bv;
    __syncthreads();
    short8 af = *(const short8*)&Al[wave * 16 + l15][quad * 8];
#pragma unroll
    for (int cb = 0; cb < 4; cb++) {
      short8 bf = *(const short8*)&Bl[cb * 16 + l15][quad * 8];
      acc[cb] = MFMA(af, bf, acc[cb]);
    }
  }
#pragma unroll
  for (int cb = 0; cb < 4; cb++) {
#pragma unroll
    for (int r = 0; r < 4; r++) {
      long row = row0 + wave * 16 + quad * 4 + r;
      long col = col0 + cb * 16 + l15;
      Ob[row * (long)Nc + col] = f2bf(acc[cb][r]);
    }
  }
}

// ---------------------------------------------------------------------------
// Phase 3: flash attention, KV-split. Flat grid 512: F&15 = combo (sp,b) so
// all q-tiles of a combo share an XCD (F%8 const) -> K/V stream stays in L2.
// WG = 4 waves x 32 q-rows = 128 q-rows. Wave computes 2 q-blocks sharing
// each K/V fragment read (2x LDS reuse). K-tile = 32 keys, double-buffered
// via global_load_lds DMA with raw s_barrier + vmcnt(8) prefetch overlap.
// l computed via ones-column MFMA (block 16) - no sum shuffles.
// ---------------------------------------------------------------------------
__global__ __launch_bounds__(256, 2) void attn(const unsigned short* __restrict__ Qg,
                                               const unsigned short* __restrict__ Kg,
                                               const unsigned short* __restrict__ Vtg,
                                               unsigned short* __restrict__ Opart,
                                               float* __restrict__ Mp,
                                               float* __restrict__ Lp) {
  __shared__ alignas(16) unsigned short Kl[2 * 8192];   // 2 x (32 keys x 256 d)
  __shared__ alignas(16) unsigned short Vl[2 * 8192];   // 2 x (256 d x 32 keys)
  __shared__ alignas(16) unsigned short Plf[4][2][512]; // per-wave, per-qb P A-frags
  int F = blockIdx.x;
  int c = F & 15, sp = c & 3, b = c >> 2;
  long q0 = (long)(F >> 4) * 128;
  int t = threadIdx.x, wave = t >> 6, lane = t & 63, quad = lane >> 4, l15 = lane & 15;
  const unsigned short* Qb = Qg + (long)b * NN * CC;
  const unsigned short* Kb = Kg + (long)b * NN * CC;
  const unsigned short* Vb = Vtg + (long)b * CC * NN;

  // Q fragments (A-layout) for 2 q-blocks of 16 rows
  short8 qf[2][8];
#pragma unroll
  for (int qb = 0; qb < 2; qb++) {
    long qrow = q0 + wave * 32 + qb * 16 + l15;
#pragma unroll
    for (int ks = 0; ks < 8; ks++)
      qf[qb][ks] = *(const short8*)&Qb[qrow * 256 + ks * 32 + quad * 8];
  }

  floatx4 acc[2][17] = {};  // [qb][0..15]=O d-blocks, [16]=l (ones column)
  float mrow[2][4] = {{-INFINITY, -INFINITY, -INFINITY, -INFINITY},
                      {-INFINITY, -INFINITY, -INFINITY, -INFINITY}};
  short8 ones;
#pragma unroll
  for (int j = 0; j < 8; j++) ones[j] = (short)0x3F80;  // bf16 1.0

  const float sc = 0.0625f * 1.4426950408889634f;  // scale * log2(e)
  const int kbeg = sp * KSPLIT;

  // stage tile at key-offset m0 into buffer `buf` (8 DMA per wave = 8 KB)
  auto stage = [&](int m0, int buf) {
#pragma unroll
    for (int st = 0; st < 4; st++) {
      int fg = st * 4 + wave;  // wave-uniform
      dma16(&Kb[(long)(m0 + (fg >> 3) * 16 + l15) * 256 + (fg & 7) * 32 + quad * 8],
            &Kl[buf * 8192 + fg * 512]);
      dma16(&Vb[(long)(fg * 16 + l15) * NN + m0 + quad * 8],
            &Vl[buf * 8192 + fg * 512]);
    }
  };

  __builtin_amdgcn_s_waitcnt(0xF70);  // drain Q loads so vmcnt tracks DMAs only
  stage(kbeg, 0);
  MEMFENCE;

  for (int i = 0; i < NT; i++) {
    int cur = i & 1;
    int m0 = kbeg + i * 32;
    S_BARRIER;  // all waves done reading buf[!cur] (prev compute) -> overwrite ok
    MEMFENCE;
    if (i + 1 < NT) {
      stage(m0 + 32, cur ^ 1);
      MEMFENCE;
      __builtin_amdgcn_s_waitcnt(0xF78);  // vmcnt(8): my tile-i DMAs done
    } else {
      __builtin_amdgcn_s_waitcnt(0xF70);  // vmcnt(0)
    }
    S_BARRIER;  // all waves' tile-i data visible
    MEMFENCE;

    int kb = cur * 8192;
    // S = Q K^T : 2 q-blocks x 32 keys; each kf read feeds 2 MFMAs
    floatx4 s[2][2];
    {
      floatx4 z = {0.f, 0.f, 0.f, 0.f};
      s[0][0] = z; s[0][1] = z; s[1][0] = z; s[1][1] = z;
    }
#pragma unroll
    for (int fgk = 0; fgk < 16; fgk++) {
      short8 kf = *(const short8*)&Kl[kb + fgk * 512 + lane * 8];
      int mt = fgk >> 3, ks = fgk & 7;
      s[0][mt] = MFMA(qf[0][ks], kf, s[0][mt]);
      s[1][mt] = MFMA(qf[1][ks], kf, s[1][mt]);
    }

    // online softmax (exp2 domain), max via width-16 shuffles; P -> LDS A-frag
    float al[2][4];
#pragma unroll
    for (int qb = 0; qb < 2; qb++) {
#pragma unroll
      for (int r = 0; r < 4; r++) {
        s[qb][0][r] *= sc;
        s[qb][1][r] *= sc;
        float v = fmaxf(s[qb][0][r], s[qb][1][r]);
        v = fmaxf(v, __shfl_xor(v, 1));
        v = fmaxf(v, __shfl_xor(v, 2));
        v = fmaxf(v, __shfl_xor(v, 4));
        v = fmaxf(v, __shfl_xor(v, 8));
        float mn = fmaxf(mrow[qb][r], v);
        al[qb][r] = exp2f(mrow[qb][r] - mn);
        mrow[qb][r] = mn;
        unsigned short pb0 = f2bf(exp2f(s[qb][0][r] - mn));
        unsigned short pb1 = f2bf(exp2f(s[qb][1][r] - mn));
        int m = quad * 4 + r;
        Plf[wave][qb][((l15 >> 3) * 16 + m) * 8 + (l15 & 7)] = pb0;        // k=l15
        Plf[wave][qb][((2 + (l15 >> 3)) * 16 + m) * 8 + (l15 & 7)] = pb1;  // k=16+l15
      }
#pragma unroll
      for (int db = 0; db < 17; db++) {
        acc[qb][db][0] *= al[qb][0];
        acc[qb][db][1] *= al[qb][1];
        acc[qb][db][2] *= al[qb][2];
        acc[qb][db][3] *= al[qb][3];
      }
    }
    MEMFENCE;  // P writes before same-wave A-frag re-read
    short8 pf0 = *(const short8*)&Plf[wave][0][lane * 8];
    short8 pf1 = *(const short8*)&Plf[wave][1][lane * 8];
    acc[0][16] = MFMA(pf0, ones, acc[0][16]);  // l accumulation (row-sums)
    acc[1][16] = MFMA(pf1, ones, acc[1][16]);
#pragma unroll
    for (int db = 0; db < 16; db++) {
      short8 vf = *(const short8*)&Vl[kb + db * 512 + lane * 8];
      acc[0][db] = MFMA(pf0, vf, acc[0][db]);
      acc[1][db] = MFMA(pf1, vf, acc[1][db]);
    }
  }

  // epilogue: unnormalized partial O + per-row m,l (combine normalizes)
  unsigned short* Ob = Opart + (long)(b * NSPLIT + sp) * CC * NN;
#pragma unroll
  for (int qb = 0; qb < 2; qb++) {
    long nidx = q0 + wave * 32 + qb * 16 + quad * 4;
#pragma unroll
    for (int db = 0; db < 16; db++) {
      long d = db * 16 + l15;
      ushortx4 pk;
#pragma unroll
      for (int r = 0; r < 4; r++) pk[r] = f2bf(acc[qb][db][r]);
      *(ushortx4*)&Ob[d * NN + nidx] = pk;
    }
    if (l15 == 0) {
#pragma unroll
      for (int r = 0; r < 4; r++) {
        long n = nidx + r;
        Mp[(long)(b * NSPLIT + sp) * NN + n] = mrow[qb][r];
        Lp[(long)(b * NSPLIT + sp) * NN + n] = acc[qb][16][r];
      }
    }
  }
}

// ---------------------------------------------------------------------------
// Phase 4: combine the NSPLIT partials. Block = 64 d x 64 n.
// ---------------------------------------------------------------------------
__global__ __launch_bounds__(256) void combine(const unsigned short* __restrict__ Op,
                                               const float* __restrict__ Mp,
                                               const float* __restrict__ Lp,
                                               float* __restrict__ Out) {
  __shared__ float Wl[NSPLIT][64];
  int b = blockIdx.z;
  int d0 = blockIdx.y * 64, n0 = blockIdx.x * 64;
  int t = threadIdx.x;
  if (t < 64) {
    int n = n0 + t;
    float ms[NSPLIT], ls[NSPLIT];
#pragma unroll
    for (int s = 0; s < NSPLIT; s++) {
      ms[s] = Mp[(long)(b * NSPLIT + s) * NN + n];
      ls[s] = Lp[(long)(b * NSPLIT + s) * NN + n];
    }
    float M = ms[0];
#pragma unroll
    for (int s = 1; s < NSPLIT; s++) M = fmaxf(M, ms[s]);
    float es[NSPLIT], L = 0.f;
#pragma unroll
    for (int s = 0; s < NSPLIT; s++) {
      es[s] = exp2f(ms[s] - M);
      L += es[s] * ls[s];
    }
    float inv = 1.0f / L;
#pragma unroll
    for (int s = 0; s < NSPLIT; s++) Wl[s][t] = es[s] * inv;
  }
  __syncthreads();
  int tn = t & 15, td = t >> 4;
  int nb = n0 + tn * 4;
  float w[NSPLIT][4];
#pragma unroll
  for (int s = 0; s < NSPLIT; s++)
#pragma unroll
    for (int r = 0; r < 4; r++) w[s][r] = Wl[s][tn * 4 + r];
#pragma unroll
  for (int dd = 0; dd < 4; dd++) {
    int d = d0 + td * 4 + dd;
    floatx4 o = {0.f, 0.f, 0.f, 0.f};
#pragma unroll
    for (int s = 0; s < NSPLIT; s++) {
      ushortx4 pv = *(const ushortx4*)&Op[((long)(b * NSPLIT + s) * CC + d) * NN + nb];
#pragma unroll
      for (int r = 0; r < 4; r++) o[r] += w[s][r] * bf2f(pv[r]);
    }
    *(floatx4*)&Out[((long)b * CC + d) * NN + nb] = o;
  }
}

// ---------------------------------------------------------------------------
extern "C" void kernel_launch(void* const* d_in, const int* in_sizes, int n_in,
                              void* d_out, int out_size, void* d_ws, size_t ws_size,
                              hipStream_t stream) {
  const float* x = (const float*)d_in[0];
  const float* wq = (const float*)d_in[1];
  const float* wk = (const float*)d_in[2];
  const float* wv = (const float*)d_in[3];
  float* out = (float*)d_out;

  char* ws = (char*)d_ws;
  unsigned short* Qbuf = (unsigned short*)(ws);              // 8 MB (B,N,C)
  unsigned short* Kbuf = (unsigned short*)(ws + (8l << 20)); // 8 MB (B,N,C)
  unsigned short* Vt = (unsigned short*)(ws + (16l << 20));  // 8 MB (B,C,N)
  // Xbf lives at [24M,32M) during prep+gemms; Opart [24M,56M) written only by
  // attn, after Xbf is dead -> safe overlap.
  unsigned short* Xbf = (unsigned short*)(ws + (24l << 20));   // 8 MB (B,N,C)
  unsigned short* Opart = (unsigned short*)(ws + (24l << 20)); // 32 MB (B,S,C,N) bf16
  float* Mp = (float*)(ws + (56l << 20));                      // 256 KB
  float* Lp = (float*)(ws + (56l << 20) + (256l << 10));       // 256 KB
  unsigned short* Wq = (unsigned short*)(ws + (57l << 20));
  unsigned short* Wk = (unsigned short*)(ws + (57l << 20) + (1 << 17));
  unsigned short* Wv = (unsigned short*)(ws + (57l << 20) + (2 << 17));

  wcvt<<<dim3(CC * CC / 1024, 3), 256, 0, stream>>>(wq, wk, wv, Wq, Wk, Wv);
  prep_x<<<dim3(NN / 32, CC / 32, BB), dim3(32, 8), 0, stream>>>(x, Xbf);
  gemm_bt<<<dim3(CC / 64, NN / 64, BB), 256, 0, stream>>>(Xbf, (long)NN * CC, Wq, 0, Qbuf,
                                                          (long)NN * CC, CC);
  gemm_bt<<<dim3(CC / 64, NN / 64, BB), 256, 0, stream>>>(Xbf, (long)NN * CC, Wk, 0, Kbuf,
                                                          (long)NN * CC, CC);
  gemm_bt<<<dim3(NN / 64, CC / 64, BB), 256, 0, stream>>>(Wv, 0, Xbf, (long)NN * CC, Vt,
                                                          (long)CC * NN, NN);
  attn<<<dim3(512), 256, 0, stream>>>(Qbuf, Kbuf, Vt, Opart, Mp, Lp);
  combine<<<dim3(NN / 64, CC / 64, BB), 256, 0, stream>>>(Opart, Mp, Lp, out);
}

// Round 5
// 217.657 us; speedup vs baseline: 1.7082x; 1.4096x over previous
//
#include <hip/hip_runtime.h>
#include <hip/hip_bf16.h>

#define BB 4
#define CC 256
#define NN 4096
#define NSPLIT 4
#define KSPLIT (NN / NSPLIT)
#define NT (KSPLIT / 32)

typedef __attribute__((ext_vector_type(8))) short short8;
typedef __attribute__((ext_vector_type(4))) float floatx4;
typedef __attribute__((ext_vector_type(4))) unsigned short ushortx4;

__device__ __forceinline__ float bf2f(unsigned short u) {
  union { unsigned int i; float f; } cv; cv.i = ((unsigned int)u) << 16; return cv.f;
}
__device__ __forceinline__ unsigned short f2bf(float f) {
  union { __hip_bfloat16 h; unsigned short u; } cv; cv.h = __float2bfloat16(f); return cv.u;
}

#define MFMA(a, b, c) __builtin_amdgcn_mfma_f32_16x16x32_bf16((a), (b), (c), 0, 0, 0)

// async global->LDS DMA, 16B/lane, LDS dest = wave-uniform base + lane*16
__device__ __forceinline__ void dma16(const unsigned short* g, unsigned short* l) {
  __builtin_amdgcn_global_load_lds(
      (const __attribute__((address_space(1))) unsigned int*)g,
      (__attribute__((address_space(3))) unsigned int*)l, 16, 0, 0);
}
#define S_BARRIER __builtin_amdgcn_s_barrier()
#define MEMFENCE __asm__ volatile("" ::: "memory")

// ---------------------------------------------------------------------------
// Phase 0: fp32 weights -> bf16. Wq,Wk stacked into one 512x256 buffer.
// ---------------------------------------------------------------------------
__global__ __launch_bounds__(256) void wcvt(const float* __restrict__ w0,
                                            const float* __restrict__ w1,
                                            const float* __restrict__ w2,
                                            unsigned short* __restrict__ o0,
                                            unsigned short* __restrict__ o1,
                                            unsigned short* __restrict__ o2) {
  const float* w = (blockIdx.y == 0) ? w0 : (blockIdx.y == 1) ? w1 : w2;
  unsigned short* o = (blockIdx.y == 0) ? o0 : (blockIdx.y == 1) ? o1 : o2;
  int i = (blockIdx.x * 256 + threadIdx.x) * 4;
  floatx4 v = *(const floatx4*)&w[i];
  ushortx4 p;
#pragma unroll
  for (int r = 0; r < 4; r++) p[r] = f2bf(v[r]);
  *(ushortx4*)&o[i] = p;
}

// ---------------------------------------------------------------------------
// Phase 1: Xbf[b][n][c] = bf16( x[b][c][n] + PE(c, n) ), LDS transpose.
// ---------------------------------------------------------------------------
__global__ __launch_bounds__(256) void prep_x(const float* __restrict__ x,
                                              unsigned short* __restrict__ Xbf) {
  __shared__ float tile[32][33];
  int b = blockIdx.z;
  int n0 = blockIdx.x * 32, c0 = blockIdx.y * 32;
  int tx = threadIdx.x, ty = threadIdx.y;
#pragma unroll
  for (int i = 0; i < 4; i++) {
    int c = c0 + ty + i * 8;
    int n = n0 + tx;
    float v = x[((long)(b * CC + c)) * NN + n];
    int hh = n >> 6, ww = n & 63;
    int j = c & 63;
    float freq = exp2f(-0.2076205059304601f * (float)j);  // 10000^(-j/64)
    float arg = (float)((c < 128) ? ww : hh) * freq;
    v += (c & 64) ? cosf(arg) : sinf(arg);
    tile[ty + i * 8][tx] = v;
  }
  __syncthreads();
#pragma unroll
  for (int i = 0; i < 4; i++) {
    int n = n0 + ty + i * 8;
    int c = c0 + tx;
    Xbf[((long)(b * NN + n)) * CC + c] = f2bf(tile[tx][ty + i * 8]);
  }
}

// ---------------------------------------------------------------------------
// Phase 2: C = A * Bt^T bf16, K=256. 64x64 tile/WG (m92 convention).
// ---------------------------------------------------------------------------
__global__ __launch_bounds__(256, 2) void gemm_bt(const unsigned short* __restrict__ A, long asb,
                                                  const unsigned short* __restrict__ Bt, long bsb,
                                                  unsigned short* __restrict__ O, long osb,
                                                  int Nc) {
  __shared__ alignas(16) unsigned short Al[64][40];
  __shared__ alignas(16) unsigned short Bl[64][40];
  int b = blockIdx.z;
  const unsigned short* Ab = A + (long)b * asb;
  const unsigned short* Bb = Bt + (long)b * bsb;
  unsigned short* Ob = O + (long)b * osb;
  long row0 = (long)blockIdx.y * 64, col0 = (long)blockIdx.x * 64;
  int t = threadIdx.x, wave = t >> 6, lane = t & 63, quad = lane >> 4, l15 = lane & 15;
  int sr = t >> 2, sk = (t & 3) * 8;
  floatx4 acc[4] = {};
#pragma unroll
  for (int k0 = 0; k0 < 256; k0 += 32) {
    short8 av = *(const short8*)&Ab[(row0 + sr) * 256 + k0 + sk];
    short8 bv = *(const short8*)&Bb[(col0 + sr) * 256 + k0 + sk];
    __syncthreads();
    *(short8*)&Al[sr][sk] = av;
    *(short8*)&Bl[sr][sk] = bv;
    __syncthreads();
    short8 af = *(const short8*)&Al[wave * 16 + l15][quad * 8];
#pragma unroll
    for (int cb = 0; cb < 4; cb++) {
      short8 bf = *(const short8*)&Bl[cb * 16 + l15][quad * 8];
      acc[cb] = MFMA(af, bf, acc[cb]);
    }
  }
#pragma unroll
  for (int cb = 0; cb < 4; cb++) {
#pragma unroll
    for (int r = 0; r < 4; r++) {
      long row = row0 + wave * 16 + quad * 4 + r;
      long col = col0 + cb * 16 + l15;
      Ob[row * (long)Nc + col] = f2bf(acc[cb][r]);
    }
  }
}

// ---------------------------------------------------------------------------
// Phase 3: flash attention, NO online max. |s| <= ||q||*||k||*0.0625*log2e
// ~ 35 log2-units (Cauchy-Schwarz) -> p = 2^s can never overflow fp32/bf16;
// partials carry scale 2^0 so combine just sums. Deletes all shuffles, alpha,
// and acc rescaling (acc stays pure AGPR, MFMA-only).
// Flat grid 512: F&15 = (sp,b) combo -> XCD-local K/V stream. WG = 4 waves x
// 32 q-rows. 32-key tiles, double-buffered global_load_lds DMA, raw
// s_barrier + vmcnt(8). l via ones-column MFMA.
// QK layout (B,N,512): [0:256)=Q, [256:512)=K. Vt (B,C,N).
// ---------------------------------------------------------------------------
__global__ __launch_bounds__(256, 2) void attn(const unsigned short* __restrict__ QKg,
                                               const unsigned short* __restrict__ Vtg,
                                               unsigned short* __restrict__ Opart,
                                               float* __restrict__ Lp) {
  __shared__ alignas(16) unsigned short Kl[2 * 8192];   // 2 x (32 keys x 256 d)
  __shared__ alignas(16) unsigned short Vl[2 * 8192];   // 2 x (256 d x 32 keys)
  __shared__ alignas(16) unsigned short Plf[4][2][512]; // per-wave, per-qb P A-frags
  int F = blockIdx.x;
  int c = F & 15, sp = c & 3, b = c >> 2;
  long q0 = (long)(F >> 4) * 128;
  int t = threadIdx.x, wave = t >> 6, lane = t & 63, quad = lane >> 4, l15 = lane & 15;
  const unsigned short* Qb = QKg + (long)b * NN * 512;
  const unsigned short* Kb = Qb + 256;
  const unsigned short* Vb = Vtg + (long)b * CC * NN;

  // Q fragments (A-layout) for 2 q-blocks of 16 rows; row stride 512
  short8 qf[2][8];
#pragma unroll
  for (int qb = 0; qb < 2; qb++) {
    long qrow = q0 + wave * 32 + qb * 16 + l15;
#pragma unroll
    for (int ks = 0; ks < 8; ks++)
      qf[qb][ks] = *(const short8*)&Qb[qrow * 512 + ks * 32 + quad * 8];
  }

  floatx4 acc[2][17] = {};  // [qb][0..15]=O d-blocks, [16]=l (ones column)
  short8 ones;
#pragma unroll
  for (int j = 0; j < 8; j++) ones[j] = (short)0x3F80;  // bf16 1.0

  const float sc = 0.0625f * 1.4426950408889634f;  // scale * log2(e)
  const int kbeg = sp * KSPLIT;

  // stage tile at key-offset m0 into buffer `buf` (8 DMA per wave = 8 KB)
  auto stage = [&](int m0, int buf) {
#pragma unroll
    for (int st = 0; st < 4; st++) {
      int fg = st * 4 + wave;  // wave-uniform
      dma16(&Kb[(long)(m0 + (fg >> 3) * 16 + l15) * 512 + (fg & 7) * 32 + quad * 8],
            &Kl[buf * 8192 + fg * 512]);
      dma16(&Vb[(long)(fg * 16 + l15) * NN + m0 + quad * 8],
            &Vl[buf * 8192 + fg * 512]);
    }
  };

  __builtin_amdgcn_s_waitcnt(0xF70);  // drain Q loads so vmcnt tracks DMAs only
  stage(kbeg, 0);
  MEMFENCE;

  for (int i = 0; i < NT; i++) {
    int cur = i & 1;
    int m0 = kbeg + i * 32;
    S_BARRIER;  // all waves done reading buf[!cur] -> overwrite ok
    MEMFENCE;
    if (i + 1 < NT) {
      stage(m0 + 32, cur ^ 1);
      MEMFENCE;
      __builtin_amdgcn_s_waitcnt(0xF78);  // vmcnt(8): my tile-i DMAs done
    } else {
      __builtin_amdgcn_s_waitcnt(0xF70);  // vmcnt(0)
    }
    S_BARRIER;  // all waves' tile-i data visible
    MEMFENCE;

    int kb = cur * 8192;
    // S = Q K^T : 2 q-blocks x 32 keys; each kf read feeds 2 MFMAs
    floatx4 s[2][2];
    {
      floatx4 z = {0.f, 0.f, 0.f, 0.f};
      s[0][0] = z; s[0][1] = z; s[1][0] = z; s[1][1] = z;
    }
#pragma unroll
    for (int fgk = 0; fgk < 16; fgk++) {
      short8 kf = *(const short8*)&Kl[kb + fgk * 512 + lane * 8];
      int mt = fgk >> 3, ks = fgk & 7;
      s[0][mt] = MFMA(qf[0][ks], kf, s[0][mt]);
      s[1][mt] = MFMA(qf[1][ks], kf, s[1][mt]);
    }

    // p = 2^(s*sc)  (no max subtraction needed: |s*sc| <= ~35) -> LDS A-frag
#pragma unroll
    for (int qb = 0; qb < 2; qb++) {
#pragma unroll
      for (int r = 0; r < 4; r++) {
        unsigned short pb0 = f2bf(exp2f(s[qb][0][r] * sc));
        unsigned short pb1 = f2bf(exp2f(s[qb][1][r] * sc));
        int m = quad * 4 + r;
        Plf[wave][qb][((l15 >> 3) * 16 + m) * 8 + (l15 & 7)] = pb0;        // k=l15
        Plf[wave][qb][((2 + (l15 >> 3)) * 16 + m) * 8 + (l15 & 7)] = pb1;  // k=16+l15
      }
    }
    MEMFENCE;  // P writes before same-wave A-frag re-read
    short8 pf0 = *(const short8*)&Plf[wave][0][lane * 8];
    short8 pf1 = *(const short8*)&Plf[wave][1][lane * 8];
    acc[0][16] = MFMA(pf0, ones, acc[0][16]);  // l accumulation (row-sums)
    acc[1][16] = MFMA(pf1, ones, acc[1][16]);
#pragma unroll
    for (int db = 0; db < 16; db++) {
      short8 vf = *(const short8*)&Vl[kb + db * 512 + lane * 8];
      acc[0][db] = MFMA(pf0, vf, acc[0][db]);
      acc[1][db] = MFMA(pf1, vf, acc[1][db]);
    }
  }

  // epilogue: unnormalized partial O (scale 2^0) + per-row l
  unsigned short* Ob = Opart + (long)(b * NSPLIT + sp) * CC * NN;
#pragma unroll
  for (int qb = 0; qb < 2; qb++) {
    long nidx = q0 + wave * 32 + qb * 16 + quad * 4;
#pragma unroll
    for (int db = 0; db < 16; db++) {
      long d = db * 16 + l15;
      ushortx4 pk;
#pragma unroll
      for (int r = 0; r < 4; r++) pk[r] = f2bf(acc[qb][db][r]);
      *(ushortx4*)&Ob[d * NN + nidx] = pk;
    }
    if (l15 == 0) {
#pragma unroll
      for (int r = 0; r < 4; r++)
        Lp[(long)(b * NSPLIT + sp) * NN + nidx + r] = acc[qb][16][r];
    }
  }
}

// ---------------------------------------------------------------------------
// Phase 4: combine = sum partials, divide by total l. Block = 64 d x 64 n.
// ---------------------------------------------------------------------------
__global__ __launch_bounds__(256) void combine(const unsigned short* __restrict__ Op,
                                               const float* __restrict__ Lp,
                                               float* __restrict__ Out) {
  __shared__ float Wl[64];
  int b = blockIdx.z;
  int d0 = blockIdx.y * 64, n0 = blockIdx.x * 64;
  int t = threadIdx.x;
  if (t < 64) {
    int n = n0 + t;
    float L = 0.f;
#pragma unroll
    for (int s = 0; s < NSPLIT; s++) L += Lp[(long)(b * NSPLIT + s) * NN + n];
    Wl[t] = 1.0f / L;
  }
  __syncthreads();
  int tn = t & 15, td = t >> 4;
  int nb = n0 + tn * 4;
  float w[4];
#pragma unroll
  for (int r = 0; r < 4; r++) w[r] = Wl[tn * 4 + r];
#pragma unroll
  for (int dd = 0; dd < 4; dd++) {
    int d = d0 + td * 4 + dd;
    floatx4 o = {0.f, 0.f, 0.f, 0.f};
#pragma unroll
    for (int s = 0; s < NSPLIT; s++) {
      ushortx4 pv = *(const ushortx4*)&Op[((long)(b * NSPLIT + s) * CC + d) * NN + nb];
#pragma unroll
      for (int r = 0; r < 4; r++) o[r] += bf2f(pv[r]);
    }
#pragma unroll
    for (int r = 0; r < 4; r++) o[r] *= w[r];
    *(floatx4*)&Out[((long)b * CC + d) * NN + nb] = o;
  }
}

// ---------------------------------------------------------------------------
extern "C" void kernel_launch(void* const* d_in, const int* in_sizes, int n_in,
                              void* d_out, int out_size, void* d_ws, size_t ws_size,
                              hipStream_t stream) {
  const float* x = (const float*)d_in[0];
  const float* wq = (const float*)d_in[1];
  const float* wk = (const float*)d_in[2];
  const float* wv = (const float*)d_in[3];
  float* out = (float*)d_out;

  char* ws = (char*)d_ws;
  unsigned short* QKbuf = (unsigned short*)(ws);             // 16 MB (B,N,512)
  unsigned short* Vt = (unsigned short*)(ws + (16l << 20));  // 8 MB (B,C,N)
  // Xbf [24,32M) during prep+gemms; Opart [24,56M) written only by attn after
  // Xbf is dead -> safe overlap.
  unsigned short* Xbf = (unsigned short*)(ws + (24l << 20));   // 8 MB (B,N,C)
  unsigned short* Opart = (unsigned short*)(ws + (24l << 20)); // 32 MB (B,S,C,N)
  float* Lp = (float*)(ws + (56l << 20));                      // 256 KB
  unsigned short* Wqk = (unsigned short*)(ws + (57l << 20));   // 256 KB (512x256)
  unsigned short* Wv = (unsigned short*)(ws + (57l << 20) + (1 << 19));  // 128 KB

  wcvt<<<dim3(CC * CC / 1024, 3), 256, 0, stream>>>(wq, wk, wv, Wqk, Wqk + CC * CC, Wv);
  prep_x<<<dim3(NN / 32, CC / 32, BB), dim3(32, 8), 0, stream>>>(x, Xbf);
  // QK = X * [Wq;Wk]^T  (per batch: 4096x512, cols 0-255=Q, 256-511=K)
  gemm_bt<<<dim3(512 / 64, NN / 64, BB), 256, 0, stream>>>(Xbf, (long)NN * CC, Wqk, 0, QKbuf,
                                                           (long)NN * 512, 512);
  // Vt = Wv * X^T  (per batch: 256x4096)
  gemm_bt<<<dim3(NN / 64, CC / 64, BB), 256, 0, stream>>>(Wv, 0, Xbf, (long)NN * CC, Vt,
                                                          (long)CC * NN, NN);
  attn<<<dim3(512), 256, 0, stream>>>(QKbuf, Vt, Opart, Lp);
  combine<<<dim3(NN / 64, CC / 64, BB), 256, 0, stream>>>(Opart, Lp, out);
}

// Round 6
// 201.007 us; speedup vs baseline: 1.8496x; 1.0828x over previous
//
#include <hip/hip_runtime.h>
#include <hip/hip_bf16.h>

#define BB 4
#define CC 256
#define NN 4096
#define NSPLIT 4
#define KSPLIT (NN / NSPLIT)
#define NPAIR (KSPLIT / 64)

typedef __attribute__((ext_vector_type(8))) short short8;
typedef __attribute__((ext_vector_type(4))) float floatx4;
typedef __attribute__((ext_vector_type(4))) unsigned short ushortx4;

__device__ __forceinline__ float bf2f(unsigned short u) {
  union { unsigned int i; float f; } cv; cv.i = ((unsigned int)u) << 16; return cv.f;
}
__device__ __forceinline__ unsigned short f2bf(float f) {
  union { __hip_bfloat16 h; unsigned short u; } cv; cv.h = __float2bfloat16(f); return cv.u;
}

#define MFMA(a, b, c) __builtin_amdgcn_mfma_f32_16x16x32_bf16((a), (b), (c), 0, 0, 0)

// async global->LDS DMA, 16B/lane, LDS dest = wave-uniform base + lane*16
__device__ __forceinline__ void dma16(const unsigned short* g, unsigned short* l) {
  __builtin_amdgcn_global_load_lds(
      (const __attribute__((address_space(1))) unsigned int*)g,
      (__attribute__((address_space(3))) unsigned int*)l, 16, 0, 0);
}
#define S_BARRIER __builtin_amdgcn_s_barrier()
#define MEMFENCE __asm__ volatile("" ::: "memory")

// ---------------------------------------------------------------------------
// Phase 0: fp32 weights -> bf16. Wq,Wk stacked into one 512x256 buffer.
// ---------------------------------------------------------------------------
__global__ __launch_bounds__(256) void wcvt(const float* __restrict__ w0,
                                            const float* __restrict__ w1,
                                            const float* __restrict__ w2,
                                            unsigned short* __restrict__ o0,
                                            unsigned short* __restrict__ o1,
                                            unsigned short* __restrict__ o2) {
  const float* w = (blockIdx.y == 0) ? w0 : (blockIdx.y == 1) ? w1 : w2;
  unsigned short* o = (blockIdx.y == 0) ? o0 : (blockIdx.y == 1) ? o1 : o2;
  int i = (blockIdx.x * 256 + threadIdx.x) * 4;
  floatx4 v = *(const floatx4*)&w[i];
  ushortx4 p;
#pragma unroll
  for (int r = 0; r < 4; r++) p[r] = f2bf(v[r]);
  *(ushortx4*)&o[i] = p;
}

// ---------------------------------------------------------------------------
// Phase 1: Xbf[b][n][c] = bf16( x[b][c][n] + PE(c, n) ), LDS transpose.
// ---------------------------------------------------------------------------
__global__ __launch_bounds__(256) void prep_x(const float* __restrict__ x,
                                              unsigned short* __restrict__ Xbf) {
  __shared__ float tile[32][33];
  int b = blockIdx.z;
  int n0 = blockIdx.x * 32, c0 = blockIdx.y * 32;
  int tx = threadIdx.x, ty = threadIdx.y;
#pragma unroll
  for (int i = 0; i < 4; i++) {
    int c = c0 + ty + i * 8;
    int n = n0 + tx;
    float v = x[((long)(b * CC + c)) * NN + n];
    int hh = n >> 6, ww = n & 63;
    int j = c & 63;
    float freq = exp2f(-0.2076205059304601f * (float)j);  // 10000^(-j/64)
    float arg = (float)((c < 128) ? ww : hh) * freq;
    v += (c & 64) ? cosf(arg) : sinf(arg);
    tile[ty + i * 8][tx] = v;
  }
  __syncthreads();
#pragma unroll
  for (int i = 0; i < 4; i++) {
    int n = n0 + ty + i * 8;
    int c = c0 + tx;
    Xbf[((long)(b * NN + n)) * CC + c] = f2bf(tile[tx][ty + i * 8]);
  }
}

// ---------------------------------------------------------------------------
// Phase 2: C = A * Bt^T bf16, K=256. 64x64 tile/WG (m92 convention).
// ---------------------------------------------------------------------------
__global__ __launch_bounds__(256, 2) void gemm_bt(const unsigned short* __restrict__ A, long asb,
                                                  const unsigned short* __restrict__ Bt, long bsb,
                                                  unsigned short* __restrict__ O, long osb,
                                                  int Nc) {
  __shared__ alignas(16) unsigned short Al[64][40];
  __shared__ alignas(16) unsigned short Bl[64][40];
  int b = blockIdx.z;
  const unsigned short* Ab = A + (long)b * asb;
  const unsigned short* Bb = Bt + (long)b * bsb;
  unsigned short* Ob = O + (long)b * osb;
  long row0 = (long)blockIdx.y * 64, col0 = (long)blockIdx.x * 64;
  int t = threadIdx.x, wave = t >> 6, lane = t & 63, quad = lane >> 4, l15 = lane & 15;
  int sr = t >> 2, sk = (t & 3) * 8;
  floatx4 acc[4] = {};
#pragma unroll
  for (int k0 = 0; k0 < 256; k0 += 32) {
    short8 av = *(const short8*)&Ab[(row0 + sr) * 256 + k0 + sk];
    short8 bv = *(const short8*)&Bb[(col0 + sr) * 256 + k0 + sk];
    __syncthreads();
    *(short8*)&Al[sr][sk] = av;
    *(short8*)&Bl[sr][sk] = bv;
    __syncthreads();
    short8 af = *(const short8*)&Al[wave * 16 + l15][quad * 8];
#pragma unroll
    for (int cb = 0; cb < 4; cb++) {
      short8 bf = *(const short8*)&Bl[cb * 16 + l15][quad * 8];
      acc[cb] = MFMA(af, bf, acc[cb]);
    }
  }
#pragma unroll
  for (int cb = 0; cb < 4; cb++) {
#pragma unroll
    for (int r = 0; r < 4; r++) {
      long row = row0 + wave * 16 + quad * 4 + r;
      long col = col0 + cb * 16 + l15;
      Ob[row * (long)Nc + col] = f2bf(acc[cb][r]);
    }
  }
}

// ---------------------------------------------------------------------------
// Phase 3: flash attention, no online max (|s*sc| <= ~35 log2-units, safe).
// 8-wave WG = 256 q-rows; grid 256 = 1 WG/CU. 4-slot LDS ring: pairs of
// 32-key tiles; barriers once per 64-key pair; within a pair the two tile
// chains are independent (ILP hides exp2 + P-roundtrip latency).
// Prefetch pair p+1 during compute of pair p; vmcnt(8) keeps DMAs in flight
// across the barrier. l via ones-column MFMA.
// QK layout (B,N,512): [0:256)=Q, [256:512)=K. Vt (B,C,N).
// ---------------------------------------------------------------------------
__global__ __launch_bounds__(512, 1) void attn(const unsigned short* __restrict__ QKg,
                                               const unsigned short* __restrict__ Vtg,
                                               unsigned short* __restrict__ Opart,
                                               float* __restrict__ Lp) {
  __shared__ alignas(16) unsigned short Kl[4 * 8192];   // 4 slots x (32 keys x 256 d)
  __shared__ alignas(16) unsigned short Vl[4 * 8192];   // 4 slots x (256 d x 32 keys)
  __shared__ alignas(16) unsigned short Plf[8][2][512]; // per-wave, per-qb P A-frags
  int F = blockIdx.x;
  int c = F & 15, sp = c & 3, b = c >> 2;
  long q0 = (long)(F >> 4) * 256;
  int t = threadIdx.x, wave = t >> 6, lane = t & 63, quad = lane >> 4, l15 = lane & 15;
  const unsigned short* Qb = QKg + (long)b * NN * 512;
  const unsigned short* Kb = Qb + 256;
  const unsigned short* Vb = Vtg + (long)b * CC * NN;

  // Q fragments (A-layout) for 2 q-blocks of 16 rows; row stride 512
  short8 qf[2][8];
#pragma unroll
  for (int qb = 0; qb < 2; qb++) {
    long qrow = q0 + wave * 32 + qb * 16 + l15;
#pragma unroll
    for (int ks = 0; ks < 8; ks++)
      qf[qb][ks] = *(const short8*)&Qb[qrow * 512 + ks * 32 + quad * 8];
  }

  floatx4 acc[2][17] = {};  // [qb][0..15]=O d-blocks, [16]=l (ones column)
  short8 ones;
#pragma unroll
  for (int j = 0; j < 8; j++) ones[j] = (short)0x3F80;  // bf16 1.0

  const float sc = 0.0625f * 1.4426950408889634f;  // scale * log2(e)
  const int kbeg = sp * KSPLIT;

  // stage pair p (64 keys = 2 tiles) into ring half `buf`; 8 DMAs per wave
  auto stage_pair = [&](int p, int buf) {
#pragma unroll
    for (int tt = 0; tt < 2; tt++) {
      int m0 = kbeg + (p * 2 + tt) * 64 / 2;  // = kbeg + (p*2+tt)*32
      int slot = buf * 2 + tt;
#pragma unroll
      for (int st = 0; st < 2; st++) {
        int fg = st * 8 + wave;  // wave-uniform, 0..15
        dma16(&Kb[(long)(m0 + st * 16 + l15) * 512 + wave * 32 + quad * 8],
              &Kl[slot * 8192 + fg * 512]);
        dma16(&Vb[(long)(fg * 16 + l15) * NN + m0 + quad * 8],
              &Vl[slot * 8192 + fg * 512]);
      }
    }
  };

  __builtin_amdgcn_s_waitcnt(0xF70);  // drain Q loads so vmcnt tracks DMAs only
  stage_pair(0, 0);
  MEMFENCE;

  for (int p = 0; p < NPAIR; p++) {
    int buf = p & 1;
    S_BARRIER;  // all waves done reading ring half buf^1 (pair p-1) -> overwrite ok
    MEMFENCE;
    if (p + 1 < NPAIR) {
      stage_pair(p + 1, buf ^ 1);
      MEMFENCE;
      __builtin_amdgcn_s_waitcnt(0xF78);  // vmcnt(8): pair-p DMAs done
    } else {
      __builtin_amdgcn_s_waitcnt(0xF70);  // vmcnt(0)
    }
    S_BARRIER;  // pair-p data visible to all waves
    MEMFENCE;

#pragma unroll
    for (int tt = 0; tt < 2; tt++) {
      int kb = (buf * 2 + tt) * 8192;
      // S = Q K^T : 2 q-blocks x 32 keys; each kf read feeds 2 MFMAs
      floatx4 s[2][2];
      {
        floatx4 z = {0.f, 0.f, 0.f, 0.f};
        s[0][0] = z; s[0][1] = z; s[1][0] = z; s[1][1] = z;
      }
#pragma unroll
      for (int fgk = 0; fgk < 16; fgk++) {
        short8 kf = *(const short8*)&Kl[kb + fgk * 512 + lane * 8];
        int mt = fgk >> 3, ks = fgk & 7;
        s[0][mt] = MFMA(qf[0][ks], kf, s[0][mt]);
        s[1][mt] = MFMA(qf[1][ks], kf, s[1][mt]);
      }

      // p = 2^(s*sc), raw v_exp_f32; store to LDS in A-frag layout
#pragma unroll
      for (int qb = 0; qb < 2; qb++) {
#pragma unroll
        for (int r = 0; r < 4; r++) {
          unsigned short pb0 = f2bf(__builtin_amdgcn_exp2f(s[qb][0][r] * sc));
          unsigned short pb1 = f2bf(__builtin_amdgcn_exp2f(s[qb][1][r] * sc));
          int m = quad * 4 + r;
          Plf[wave][qb][((l15 >> 3) * 16 + m) * 8 + (l15 & 7)] = pb0;        // k=l15
          Plf[wave][qb][((2 + (l15 >> 3)) * 16 + m) * 8 + (l15 & 7)] = pb1;  // k=16+l15
        }
      }
      MEMFENCE;  // P writes before same-wave A-frag re-read (HW DS in-order)
      short8 pf0 = *(const short8*)&Plf[wave][0][lane * 8];
      short8 pf1 = *(const short8*)&Plf[wave][1][lane * 8];
      acc[0][16] = MFMA(pf0, ones, acc[0][16]);  // l accumulation (row-sums)
      acc[1][16] = MFMA(pf1, ones, acc[1][16]);
#pragma unroll
      for (int db = 0; db < 16; db++) {
        short8 vf = *(const short8*)&Vl[kb + db * 512 + lane * 8];
        acc[0][db] = MFMA(pf0, vf, acc[0][db]);
        acc[1][db] = MFMA(pf1, vf, acc[1][db]);
      }
      MEMFENCE;  // tile tt+1 P writes must stay after tile tt's pf reads
    }
  }

  // epilogue: unnormalized partial O (scale 2^0) + per-row l
  unsigned short* Ob = Opart + (long)(b * NSPLIT + sp) * CC * NN;
#pragma unroll
  for (int qb = 0; qb < 2; qb++) {
    long nidx = q0 + wave * 32 + qb * 16 + quad * 4;
#pragma unroll
    for (int db = 0; db < 16; db++) {
      long d = db * 16 + l15;
      ushortx4 pk;
#pragma unroll
      for (int r = 0; r < 4; r++) pk[r] = f2bf(acc[qb][db][r]);
      *(ushortx4*)&Ob[d * NN + nidx] = pk;
    }
    if (l15 == 0) {
#pragma unroll
      for (int r = 0; r < 4; r++)
        Lp[(long)(b * NSPLIT + sp) * NN + nidx + r] = acc[qb][16][r];
    }
  }
}

// ---------------------------------------------------------------------------
// Phase 4: combine = sum partials, divide by total l. Block = 64 d x 64 n.
// ---------------------------------------------------------------------------
__global__ __launch_bounds__(256) void combine(const unsigned short* __restrict__ Op,
                                               const float* __restrict__ Lp,
                                               float* __restrict__ Out) {
  __shared__ float Wl[64];
  int b = blockIdx.z;
  int d0 = blockIdx.y * 64, n0 = blockIdx.x * 64;
  int t = threadIdx.x;
  if (t < 64) {
    int n = n0 + t;
    float L = 0.f;
#pragma unroll
    for (int s = 0; s < NSPLIT; s++) L += Lp[(long)(b * NSPLIT + s) * NN + n];
    Wl[t] = 1.0f / L;
  }
  __syncthreads();
  int tn = t & 15, td = t >> 4;
  int nb = n0 + tn * 4;
  float w[4];
#pragma unroll
  for (int r = 0; r < 4; r++) w[r] = Wl[tn * 4 + r];
#pragma unroll
  for (int dd = 0; dd < 4; dd++) {
    int d = d0 + td * 4 + dd;
    floatx4 o = {0.f, 0.f, 0.f, 0.f};
#pragma unroll
    for (int s = 0; s < NSPLIT; s++) {
      ushortx4 pv = *(const ushortx4*)&Op[((long)(b * NSPLIT + s) * CC + d) * NN + nb];
#pragma unroll
      for (int r = 0; r < 4; r++) o[r] += bf2f(pv[r]);
    }
#pragma unroll
    for (int r = 0; r < 4; r++) o[r] *= w[r];
    *(floatx4*)&Out[((long)b * CC + d) * NN + nb] = o;
  }
}

// ---------------------------------------------------------------------------
extern "C" void kernel_launch(void* const* d_in, const int* in_sizes, int n_in,
                              void* d_out, int out_size, void* d_ws, size_t ws_size,
                              hipStream_t stream) {
  const float* x = (const float*)d_in[0];
  const float* wq = (const float*)d_in[1];
  const float* wk = (const float*)d_in[2];
  const float* wv = (const float*)d_in[3];
  float* out = (float*)d_out;

  char* ws = (char*)d_ws;
  unsigned short* QKbuf = (unsigned short*)(ws);             // 16 MB (B,N,512)
  unsigned short* Vt = (unsigned short*)(ws + (16l << 20));  // 8 MB (B,C,N)
  // Xbf [24,32M) during prep+gemms; Opart [24,56M) written only by attn after
  // Xbf is dead -> safe overlap.
  unsigned short* Xbf = (unsigned short*)(ws + (24l << 20));   // 8 MB (B,N,C)
  unsigned short* Opart = (unsigned short*)(ws + (24l << 20)); // 32 MB (B,S,C,N)
  float* Lp = (float*)(ws + (56l << 20));                      // 256 KB
  unsigned short* Wqk = (unsigned short*)(ws + (57l << 20));   // 256 KB (512x256)
  unsigned short* Wv = (unsigned short*)(ws + (57l << 20) + (1 << 19));  // 128 KB

  wcvt<<<dim3(CC * CC / 1024, 3), 256, 0, stream>>>(wq, wk, wv, Wqk, Wqk + CC * CC, Wv);
  prep_x<<<dim3(NN / 32, CC / 32, BB), dim3(32, 8), 0, stream>>>(x, Xbf);
  // QK = X * [Wq;Wk]^T  (per batch: 4096x512, cols 0-255=Q, 256-511=K)
  gemm_bt<<<dim3(512 / 64, NN / 64, BB), 256, 0, stream>>>(Xbf, (long)NN * CC, Wqk, 0, QKbuf,
                                                           (long)NN * 512, 512);
  // Vt = Wv * X^T  (per batch: 256x4096)
  gemm_bt<<<dim3(NN / 64, CC / 64, BB), 256, 0, stream>>>(Wv, 0, Xbf, (long)NN * CC, Vt,
                                                          (long)CC * NN, NN);
  attn<<<dim3(256), 512, 0, stream>>>(QKbuf, Vt, Opart, Lp);
  combine<<<dim3(NN / 64, CC / 64, BB), 256, 0, stream>>>(Opart, Lp, out);
}

// Round 7
// 194.073 us; speedup vs baseline: 1.9157x; 1.0357x over previous
//
#include <hip/hip_runtime.h>
#include <hip/hip_bf16.h>

#define BB 4
#define CC 256
#define NN 4096
#define NSPLIT 4
#define KSPLIT (NN / NSPLIT)
#define NPAIR (KSPLIT / 64)

typedef __attribute__((ext_vector_type(8))) short short8;
typedef __attribute__((ext_vector_type(4))) float floatx4;
typedef __attribute__((ext_vector_type(4))) unsigned short ushortx4;

__device__ __forceinline__ float bf2f(unsigned short u) {
  union { unsigned int i; float f; } cv; cv.i = ((unsigned int)u) << 16; return cv.f;
}
__device__ __forceinline__ unsigned short f2bf(float f) {
  union { __hip_bfloat16 h; unsigned short u; } cv; cv.h = __float2bfloat16(f); return cv.u;
}

#define MFMA(a, b, c) __builtin_amdgcn_mfma_f32_16x16x32_bf16((a), (b), (c), 0, 0, 0)

// async global->LDS DMA, 16B/lane, LDS dest = wave-uniform base + lane*16
__device__ __forceinline__ void dma16(const unsigned short* g, unsigned short* l) {
  __builtin_amdgcn_global_load_lds(
      (const __attribute__((address_space(1))) unsigned int*)g,
      (__attribute__((address_space(3))) unsigned int*)l, 16, 0, 0);
}
#define S_BARRIER __builtin_amdgcn_s_barrier()
#define MEMFENCE __asm__ volatile("" ::: "memory")

// ---------------------------------------------------------------------------
// Phase 0: fp32 weights -> bf16. Wq,Wk stacked into one 512x256 buffer.
// ---------------------------------------------------------------------------
__global__ __launch_bounds__(256) void wcvt(const float* __restrict__ w0,
                                            const float* __restrict__ w1,
                                            const float* __restrict__ w2,
                                            unsigned short* __restrict__ o0,
                                            unsigned short* __restrict__ o1,
                                            unsigned short* __restrict__ o2) {
  const float* w = (blockIdx.y == 0) ? w0 : (blockIdx.y == 1) ? w1 : w2;
  unsigned short* o = (blockIdx.y == 0) ? o0 : (blockIdx.y == 1) ? o1 : o2;
  int i = (blockIdx.x * 256 + threadIdx.x) * 4;
  floatx4 v = *(const floatx4*)&w[i];
  ushortx4 p;
#pragma unroll
  for (int r = 0; r < 4; r++) p[r] = f2bf(v[r]);
  *(ushortx4*)&o[i] = p;
}

// ---------------------------------------------------------------------------
// Phase 1: Xbf[b][n][c] = bf16( x[b][c][n] + PE(c, n) ), LDS transpose.
// ---------------------------------------------------------------------------
__global__ __launch_bounds__(256) void prep_x(const float* __restrict__ x,
                                              unsigned short* __restrict__ Xbf) {
  __shared__ float tile[32][33];
  int b = blockIdx.z;
  int n0 = blockIdx.x * 32, c0 = blockIdx.y * 32;
  int tx = threadIdx.x, ty = threadIdx.y;
#pragma unroll
  for (int i = 0; i < 4; i++) {
    int c = c0 + ty + i * 8;
    int n = n0 + tx;
    float v = x[((long)(b * CC + c)) * NN + n];
    int hh = n >> 6, ww = n & 63;
    int j = c & 63;
    float freq = exp2f(-0.2076205059304601f * (float)j);  // 10000^(-j/64)
    float arg = (float)((c < 128) ? ww : hh) * freq;
    v += (c & 64) ? cosf(arg) : sinf(arg);
    tile[ty + i * 8][tx] = v;
  }
  __syncthreads();
#pragma unroll
  for (int i = 0; i < 4; i++) {
    int n = n0 + ty + i * 8;
    int c = c0 + tx;
    Xbf[((long)(b * NN + n)) * CC + c] = f2bf(tile[tx][ty + i * 8]);
  }
}

// ---------------------------------------------------------------------------
// Phase 2 (m97-class): fused 128x128-tile GEMM, C = A * Bt^T, K=256, bf16.
// Flat grid 768: F<512 -> QK = Xbf * Wqk^T (4096x512/batch);
//                F>=512 -> Vt = Wv * Xbf^T (256x4096/batch).
// 4 waves; wave (wr,wc) owns 64x64 = 4x4 16x16 accs. Fragment-major LDS,
// double-buffered global_load_lds (width 16), per-wave vmcnt(4) + barrier.
// ---------------------------------------------------------------------------
__global__ __launch_bounds__(256, 2) void gemm_fused(const unsigned short* __restrict__ Xbf,
                                                     const unsigned short* __restrict__ Wqk,
                                                     const unsigned short* __restrict__ Wv,
                                                     unsigned short* __restrict__ QK,
                                                     unsigned short* __restrict__ Vt) {
  __shared__ alignas(16) unsigned short Af[2][8 * 512];  // 8 KB per buf
  __shared__ alignas(16) unsigned short Bf[2][8 * 512];
  const unsigned short *Ab, *Bb;
  unsigned short* Ob;
  long row0, col0;
  int ldo;
  int F = blockIdx.x;
  if (F < 512) {  // QK projection: A=Xbf(4096x256), Bt=Wqk(512x256), O=(B,N,512)
    int b = F >> 7, r = F & 127;
    row0 = (long)(r >> 2) * 128;  // 32 row tiles
    col0 = (long)(r & 3) * 128;   // 4 col tiles
    Ab = Xbf + (long)b * NN * CC;
    Bb = Wqk;
    Ob = QK + (long)b * NN * 512;
    ldo = 512;
  } else {  // Vt: A=Wv(256x256), Bt=Xbf(4096x256), O=(B,C,N)
    int F2 = F - 512;
    int b = F2 >> 6, r = F2 & 63;
    row0 = (long)(r >> 5) * 128;  // 2 row tiles
    col0 = (long)(r & 31) * 128;  // 32 col tiles
    Ab = Wv;
    Bb = Xbf + (long)b * NN * CC;
    Ob = Vt + (long)b * CC * NN;
    ldo = NN;
  }
  int t = threadIdx.x, wave = t >> 6, lane = t & 63, quad = lane >> 4, l15 = lane & 15;
  int wr = wave >> 1, wc = wave & 1;

  // stage k-chunk [k0,k0+32) into buffer `buf`: 16 fragment-groups, 4/wave
  auto stage = [&](int k0, int buf) {
#pragma unroll
    for (int i = 0; i < 2; i++) {
      int fg = wave * 2 + i;  // 0..7, wave-uniform
      dma16(&Ab[(row0 + fg * 16 + l15) * 256 + k0 + quad * 8], &Af[buf][fg * 512]);
      dma16(&Bb[(col0 + fg * 16 + l15) * 256 + k0 + quad * 8], &Bf[buf][fg * 512]);
    }
  };

  floatx4 acc[4][4] = {};
  stage(0, 0);
  MEMFENCE;
#pragma unroll
  for (int ki = 0; ki < 8; ki++) {
    int buf = ki & 1;
    S_BARRIER;  // all waves done reading buf (from step ki-2) -> overwrite ok
    MEMFENCE;
    if (ki + 1 < 8) {
      stage((ki + 1) * 32, buf ^ 1);
      MEMFENCE;
      __builtin_amdgcn_s_waitcnt(0xF74);  // vmcnt(4): my step-ki DMAs done
    } else {
      __builtin_amdgcn_s_waitcnt(0xF70);  // vmcnt(0)
    }
    S_BARRIER;  // step-ki fragments visible to all waves
    MEMFENCE;
    short8 af[4], bf[4];
#pragma unroll
    for (int i = 0; i < 4; i++) {
      af[i] = *(const short8*)&Af[buf][(wr * 4 + i) * 512 + lane * 8];
      bf[i] = *(const short8*)&Bf[buf][(wc * 4 + i) * 512 + lane * 8];
    }
#pragma unroll
    for (int i = 0; i < 4; i++)
#pragma unroll
      for (int j = 0; j < 4; j++) acc[i][j] = MFMA(af[i], bf[j], acc[i][j]);
  }

  // C/D layout (m89): col = l15, row = quad*4 + r (within each 16x16 block)
#pragma unroll
  for (int i = 0; i < 4; i++)
#pragma unroll
    for (int j = 0; j < 4; j++) {
      long col = col0 + (wc * 4 + j) * 16 + l15;
#pragma unroll
      for (int r = 0; r < 4; r++) {
        long row = row0 + (wr * 4 + i) * 16 + quad * 4 + r;
        Ob[row * (long)ldo + col] = f2bf(acc[i][j][r]);
      }
    }
}

// ---------------------------------------------------------------------------
// Phase 3: flash attention, no online max (|s*sc| <= ~35 log2-units, safe).
// 8-wave WG = 256 q-rows; grid 256 = 1 WG/CU. 4-slot LDS ring: pairs of
// 32-key tiles; barriers once per 64-key pair; within a pair the two tile
// chains are independent (ILP hides exp2 + P-roundtrip latency).
// QK layout (B,N,512): [0:256)=Q, [256:512)=K. Vt (B,C,N).
// ---------------------------------------------------------------------------
__global__ __launch_bounds__(512, 1) void attn(const unsigned short* __restrict__ QKg,
                                               const unsigned short* __restrict__ Vtg,
                                               unsigned short* __restrict__ Opart,
                                               float* __restrict__ Lp) {
  __shared__ alignas(16) unsigned short Kl[4 * 8192];   // 4 slots x (32 keys x 256 d)
  __shared__ alignas(16) unsigned short Vl[4 * 8192];   // 4 slots x (256 d x 32 keys)
  __shared__ alignas(16) unsigned short Plf[8][2][512]; // per-wave, per-qb P A-frags
  int F = blockIdx.x;
  int c = F & 15, sp = c & 3, b = c >> 2;
  long q0 = (long)(F >> 4) * 256;
  int t = threadIdx.x, wave = t >> 6, lane = t & 63, quad = lane >> 4, l15 = lane & 15;
  const unsigned short* Qb = QKg + (long)b * NN * 512;
  const unsigned short* Kb = Qb + 256;
  const unsigned short* Vb = Vtg + (long)b * CC * NN;

  // Q fragments (A-layout) for 2 q-blocks of 16 rows; row stride 512
  short8 qf[2][8];
#pragma unroll
  for (int qb = 0; qb < 2; qb++) {
    long qrow = q0 + wave * 32 + qb * 16 + l15;
#pragma unroll
    for (int ks = 0; ks < 8; ks++)
      qf[qb][ks] = *(const short8*)&Qb[qrow * 512 + ks * 32 + quad * 8];
  }

  floatx4 acc[2][17] = {};  // [qb][0..15]=O d-blocks, [16]=l (ones column)
  short8 ones;
#pragma unroll
  for (int j = 0; j < 8; j++) ones[j] = (short)0x3F80;  // bf16 1.0

  const float sc = 0.0625f * 1.4426950408889634f;  // scale * log2(e)
  const int kbeg = sp * KSPLIT;

  // stage pair p (64 keys = 2 tiles) into ring half `buf`; 8 DMAs per wave
  auto stage_pair = [&](int p, int buf) {
#pragma unroll
    for (int tt = 0; tt < 2; tt++) {
      int m0 = kbeg + (p * 2 + tt) * 32;
      int slot = buf * 2 + tt;
#pragma unroll
      for (int st = 0; st < 2; st++) {
        int fg = st * 8 + wave;  // wave-uniform, 0..15
        dma16(&Kb[(long)(m0 + st * 16 + l15) * 512 + wave * 32 + quad * 8],
              &Kl[slot * 8192 + fg * 512]);
        dma16(&Vb[(long)(fg * 16 + l15) * NN + m0 + quad * 8],
              &Vl[slot * 8192 + fg * 512]);
      }
    }
  };

  __builtin_amdgcn_s_waitcnt(0xF70);  // drain Q loads so vmcnt tracks DMAs only
  stage_pair(0, 0);
  MEMFENCE;

  for (int p = 0; p < NPAIR; p++) {
    int buf = p & 1;
    S_BARRIER;  // all waves done reading ring half buf^1 -> overwrite ok
    MEMFENCE;
    if (p + 1 < NPAIR) {
      stage_pair(p + 1, buf ^ 1);
      MEMFENCE;
      __builtin_amdgcn_s_waitcnt(0xF78);  // vmcnt(8): pair-p DMAs done
    } else {
      __builtin_amdgcn_s_waitcnt(0xF70);  // vmcnt(0)
    }
    S_BARRIER;  // pair-p data visible to all waves
    MEMFENCE;

#pragma unroll
    for (int tt = 0; tt < 2; tt++) {
      int kb = (buf * 2 + tt) * 8192;
      // S = Q K^T : 2 q-blocks x 32 keys; each kf read feeds 2 MFMAs
      floatx4 s[2][2];
      {
        floatx4 z = {0.f, 0.f, 0.f, 0.f};
        s[0][0] = z; s[0][1] = z; s[1][0] = z; s[1][1] = z;
      }
#pragma unroll
      for (int fgk = 0; fgk < 16; fgk++) {
        short8 kf = *(const short8*)&Kl[kb + fgk * 512 + lane * 8];
        int mt = fgk >> 3, ks = fgk & 7;
        s[0][mt] = MFMA(qf[0][ks], kf, s[0][mt]);
        s[1][mt] = MFMA(qf[1][ks], kf, s[1][mt]);
      }

      // p = 2^(s*sc), raw v_exp_f32; store to LDS in A-frag layout
#pragma unroll
      for (int qb = 0; qb < 2; qb++) {
#pragma unroll
        for (int r = 0; r < 4; r++) {
          unsigned short pb0 = f2bf(__builtin_amdgcn_exp2f(s[qb][0][r] * sc));
          unsigned short pb1 = f2bf(__builtin_amdgcn_exp2f(s[qb][1][r] * sc));
          int m = quad * 4 + r;
          Plf[wave][qb][((l15 >> 3) * 16 + m) * 8 + (l15 & 7)] = pb0;        // k=l15
          Plf[wave][qb][((2 + (l15 >> 3)) * 16 + m) * 8 + (l15 & 7)] = pb1;  // k=16+l15
        }
      }
      MEMFENCE;  // P writes before same-wave A-frag re-read (HW DS in-order)
      short8 pf0 = *(const short8*)&Plf[wave][0][lane * 8];
      short8 pf1 = *(const short8*)&Plf[wave][1][lane * 8];
      acc[0][16] = MFMA(pf0, ones, acc[0][16]);  // l accumulation (row-sums)
      acc[1][16] = MFMA(pf1, ones, acc[1][16]);
#pragma unroll
      for (int db = 0; db < 16; db++) {
        short8 vf = *(const short8*)&Vl[kb + db * 512 + lane * 8];
        acc[0][db] = MFMA(pf0, vf, acc[0][db]);
        acc[1][db] = MFMA(pf1, vf, acc[1][db]);
      }
      MEMFENCE;  // tile tt+1 P writes must stay after tile tt's pf reads
    }
  }

  // epilogue: unnormalized partial O (scale 2^0) + per-row l
  unsigned short* Ob = Opart + (long)(b * NSPLIT + sp) * CC * NN;
#pragma unroll
  for (int qb = 0; qb < 2; qb++) {
    long nidx = q0 + wave * 32 + qb * 16 + quad * 4;
#pragma unroll
    for (int db = 0; db < 16; db++) {
      long d = db * 16 + l15;
      ushortx4 pk;
#pragma unroll
      for (int r = 0; r < 4; r++) pk[r] = f2bf(acc[qb][db][r]);
      *(ushortx4*)&Ob[d * NN + nidx] = pk;
    }
    if (l15 == 0) {
#pragma unroll
      for (int r = 0; r < 4; r++)
        Lp[(long)(b * NSPLIT + sp) * NN + nidx + r] = acc[qb][16][r];
    }
  }
}

// ---------------------------------------------------------------------------
// Phase 4: combine = sum partials, divide by total l. Block = 64 d x 64 n.
// ---------------------------------------------------------------------------
__global__ __launch_bounds__(256) void combine(const unsigned short* __restrict__ Op,
                                               const float* __restrict__ Lp,
                                               float* __restrict__ Out) {
  __shared__ float Wl[64];
  int b = blockIdx.z;
  int d0 = blockIdx.y * 64, n0 = blockIdx.x * 64;
  int t = threadIdx.x;
  if (t < 64) {
    int n = n0 + t;
    float L = 0.f;
#pragma unroll
    for (int s = 0; s < NSPLIT; s++) L += Lp[(long)(b * NSPLIT + s) * NN + n];
    Wl[t] = 1.0f / L;
  }
  __syncthreads();
  int tn = t & 15, td = t >> 4;
  int nb = n0 + tn * 4;
  float w[4];
#pragma unroll
  for (int r = 0; r < 4; r++) w[r] = Wl[tn * 4 + r];
#pragma unroll
  for (int dd = 0; dd < 4; dd++) {
    int d = d0 + td * 4 + dd;
    floatx4 o = {0.f, 0.f, 0.f, 0.f};
#pragma unroll
    for (int s = 0; s < NSPLIT; s++) {
      ushortx4 pv = *(const ushortx4*)&Op[((long)(b * NSPLIT + s) * CC + d) * NN + nb];
#pragma unroll
      for (int r = 0; r < 4; r++) o[r] += bf2f(pv[r]);
    }
#pragma unroll
    for (int r = 0; r < 4; r++) o[r] *= w[r];
    *(floatx4*)&Out[((long)b * CC + d) * NN + nb] = o;
  }
}

// ---------------------------------------------------------------------------
extern "C" void kernel_launch(void* const* d_in, const int* in_sizes, int n_in,
                              void* d_out, int out_size, void* d_ws, size_t ws_size,
                              hipStream_t stream) {
  const float* x = (const float*)d_in[0];
  const float* wq = (const float*)d_in[1];
  const float* wk = (const float*)d_in[2];
  const float* wv = (const float*)d_in[3];
  float* out = (float*)d_out;

  char* ws = (char*)d_ws;
  unsigned short* QKbuf = (unsigned short*)(ws);             // 16 MB (B,N,512)
  unsigned short* Vt = (unsigned short*)(ws + (16l << 20));  // 8 MB (B,C,N)
  // Xbf [24,32M) during prep+gemms; Opart [24,56M) written only by attn after
  // Xbf is dead -> safe overlap.
  unsigned short* Xbf = (unsigned short*)(ws + (24l << 20));   // 8 MB (B,N,C)
  unsigned short* Opart = (unsigned short*)(ws + (24l << 20)); // 32 MB (B,S,C,N)
  float* Lp = (float*)(ws + (56l << 20));                      // 256 KB
  unsigned short* Wqk = (unsigned short*)(ws + (57l << 20));   // 256 KB (512x256)
  unsigned short* Wv = (unsigned short*)(ws + (57l << 20) + (1 << 19));  // 128 KB

  wcvt<<<dim3(CC * CC / 1024, 3), 256, 0, stream>>>(wq, wk, wv, Wqk, Wqk + CC * CC, Wv);
  prep_x<<<dim3(NN / 32, CC / 32, BB), dim3(32, 8), 0, stream>>>(x, Xbf);
  gemm_fused<<<dim3(768), 256, 0, stream>>>(Xbf, Wqk, Wv, QKbuf, Vt);
  attn<<<dim3(256), 512, 0, stream>>>(QKbuf, Vt, Opart, Lp);
  combine<<<dim3(NN / 64, CC / 64, BB), 256, 0, stream>>>(Opart, Lp, out);
}